// Round 1
// baseline (338.954 us; speedup 1.0000x reference)
//
#include <hip/hip_runtime.h>

// MultiBoxLoss_four_corners — B=64, P=8732, C=81, NEG_POS_RATIO=3
// Outputs: (loss_l/N, loss_c/N, loss_four_corners/N) -> d_out[0..2] (f32)
//
// R3: CE conf-row reads were uncoalesced (each thread streamed its own 324B
// row -> 64 cache lines per VMEM instr, latency-bound at 19% HBM BW).
// Now: LDS-stage 64 rows/phase with coalesced float4 loads (alignment-phase
// corrected), 4 threads/row exp-sum from LDS + 2x shfl_xor combine.
// k_batch general top-K path retained (only runs when mining is selective).

#define NB 64
#define NP 8732
#define NC 81
constexpr int BP = NB * NP;              // 558848
constexpr int PBLK = (NP + 255) / 256;   // 35 blocks per batch (tail 28)

__device__ inline float sl1(float d) {
    d = fabsf(d);
    return d < 1.0f ? 0.5f * d * d : d - 0.5f;
}

// ws layout: ce[BP] | acc[2] | npos_b[64](int) | spos_b[64] | sneg_b[64] | loss_c_b[64]
__global__ void k_init(float* acc_area) {
    // zero acc[2] + npos_b + spos_b + sneg_b  (2 + 192 words)
    if (threadIdx.x < 194) acc_area[threadIdx.x] = 0.0f;
}

__global__ __launch_bounds__(256) void k_main(
    const float* __restrict__ loc_data, const float* __restrict__ conf_data,
    const float* __restrict__ fc_data,  const float* __restrict__ loc_t,
    const float* __restrict__ fc_t,     const int* __restrict__ conf_t,
    float* __restrict__ ce, float* __restrict__ acc,
    int* __restrict__ npos_b, float* __restrict__ spos_b, float* __restrict__ sneg_b)
{
    const int b  = blockIdx.y;
    const int t  = threadIdx.x;
    const int p0 = blockIdx.x << 8;
    const int nrows = min(256, NP - p0);     // 256, tail block 28

    __shared__ __align__(16) float tile[64 * NC + 4];   // one 64-row stage (20.75 KB)
    __shared__ int   tgt_s[256];
    __shared__ float red[4][5];

    float l_sum = 0.0f, f_sum = 0.0f, sp = 0.0f, sn = 0.0f;
    int np = 0;

    // ---- per-prior smooth-L1 (coalesced float4) + stash targets ----
    {
        const int p = p0 + t;
        int tgt = 0;
        if (p < NP) {
            const size_t g = (size_t)b * NP + p;
            tgt = conf_t[g];
            const float posf = (tgt > 0) ? 1.0f : 0.0f;
            np = (tgt > 0) ? 1 : 0;
            float4 a4  = ((const float4*)loc_data)[g];
            float4 a4t = ((const float4*)loc_t)[g];
            l_sum = (sl1(a4.x - a4t.x) + sl1(a4.y - a4t.y) +
                     sl1(a4.z - a4t.z) + sl1(a4.w - a4t.w)) * posf;
            float4 c0 = ((const float4*)fc_data)[2 * g];
            float4 c1 = ((const float4*)fc_data)[2 * g + 1];
            float4 d0 = ((const float4*)fc_t)[2 * g];
            float4 d1 = ((const float4*)fc_t)[2 * g + 1];
            f_sum = (sl1(c0.x - d0.x) + sl1(c0.y - d0.y) + sl1(c0.z - d0.z) + sl1(c0.w - d0.w) +
                     sl1(c1.x - d1.x) + sl1(c1.y - d1.y) + sl1(c1.z - d1.z) + sl1(c1.w - d1.w)) * posf;
        }
        tgt_s[t] = tgt;
    }

    // ---- CE: LDS-staged, coalesced ----
    // Block's conf chunk starts at float index gbase; rows are 324B (not 16B-
    // aligned). Stage from the 16B-aligned base (phase al in [0,4)); each
    // 64-row stage advances by 64*81=5184 floats (mult of 4), so al is
    // block-constant.
    const size_t gbase = ((size_t)b * NP + p0) * (size_t)NC;
    const int al = (int)(gbase & 3);
    const float* conf_al = conf_data + (gbase - (size_t)al);  // 16B-aligned
    const int r = t >> 2, sub = t & 3;

    for (int s = 0; s < 4; ++s) {
        const int r0 = s << 6;
        const int rs = min(64, nrows - r0);
        if (rs <= 0) break;                       // block-uniform
        const int nf  = al + rs * NC;             // floats to stage this phase
        const int n4  = nf >> 2;
        const int rem = nf & 3;

        __syncthreads();                          // tile free from prev phase
        const float4* src4 = (const float4*)(conf_al + (size_t)r0 * NC);
        float4* dst4 = (float4*)tile;
        for (int j = t; j < n4; j += 256) dst4[j] = src4[j];
        if (t < rem) tile[(n4 << 2) + t] = conf_al[(size_t)r0 * NC + (n4 << 2) + t];
        __syncthreads();

        if (r < rs) {
            const float* lrow = tile + al + r * NC;   // 81 floats for this row
            float s0 = 0.0f, s1 = 0.0f;
            int c = sub;                               // sub + 4k interleave
            #pragma unroll
            for (int k = 0; k < 10; ++k) {
                s0 += __expf(lrow[c]); c += 4;
                s1 += __expf(lrow[c]); c += 4;
            }
            if (sub == 0) s0 += __expf(lrow[80]);
            float ss = s0 + s1;
            ss += __shfl_xor(ss, 1, 64);               // 4-lane group combine
            ss += __shfl_xor(ss, 2, 64);
            if (sub == 0) {
                const int tgt = tgt_s[r0 + r];
                const float cev = __logf(ss) - lrow[tgt];
                ce[(size_t)b * NP + (size_t)(p0 + r0 + r)] = cev;
                if (tgt > 0) sp += cev; else sn += cev;
            }
        }
    }

    // ---- block reduce 5 values -> atomics ----
    const int wave = t >> 6, lane = t & 63;
    float vnp = (float)np;
    #pragma unroll
    for (int o = 32; o; o >>= 1) {
        l_sum += __shfl_xor(l_sum, o, 64);
        f_sum += __shfl_xor(f_sum, o, 64);
        sp    += __shfl_xor(sp, o, 64);
        sn    += __shfl_xor(sn, o, 64);
        vnp   += __shfl_xor(vnp, o, 64);
    }
    if (lane == 0) {
        red[wave][0] = l_sum; red[wave][1] = f_sum;
        red[wave][2] = sp;    red[wave][3] = sn;   red[wave][4] = vnp;
    }
    __syncthreads();
    if (t == 0) {
        float rl = 0, rf = 0, rp = 0, rn = 0, rc = 0;
        #pragma unroll
        for (int w = 0; w < 4; ++w) {
            rl += red[w][0]; rf += red[w][1]; rp += red[w][2];
            rn += red[w][3]; rc += red[w][4];
        }
        atomicAdd(&acc[0], rl);
        atomicAdd(&acc[1], rf);
        atomicAdd(&spos_b[b], rp);
        atomicAdd(&sneg_b[b], rn);
        atomicAdd(&npos_b[b], (int)rc);
    }
}

// One block per batch. Common path: O(1). Rare path: top-K via bit binary search.
__global__ __launch_bounds__(256) void k_batch(
    const float* __restrict__ ce, const int* __restrict__ conf_t,
    const int* __restrict__ npos_b, const float* __restrict__ spos_b,
    const float* __restrict__ sneg_b, float* __restrict__ loss_c_b)
{
    const int b = blockIdx.x;
    const int t = threadIdx.x;
    const int npos    = npos_b[b];
    const int nneg    = NP - npos;
    const int num_neg = min(3 * npos, NP - 1);

    if (num_neg >= nneg) {              // all negatives selected (this dataset)
        if (t == 0) loss_c_b[b] = spos_b[b] + sneg_b[b];
        return;
    }
    if (num_neg <= 0) {
        if (t == 0) loss_c_b[b] = spos_b[b];
        return;
    }

    // general path: stage negative CE into LDS (positives -> -1), top-K sum
    __shared__ float ce_s[NP];
    __shared__ float sredf[4];
    __shared__ int   sredi[4];
    const float* crow = ce + (size_t)b * NP;
    const int*   trow = conf_t + (size_t)b * NP;
    for (int p = t; p < NP; p += 256)
        ce_s[p] = (trow[p] > 0) ? -1.0f : crow[p];
    __syncthreads();

    const int wave = t >> 6, lane = t & 63;
    const int K = num_neg;
    unsigned lo = 0u, hi = 0x7f800000u;
    while (lo < hi) {
        unsigned mid = lo + ((hi - lo) >> 1);
        float v = __uint_as_float(mid);
        int c_t = 0;
        for (int p = t; p < NP; p += 256) c_t += (ce_s[p] > v) ? 1 : 0;
        #pragma unroll
        for (int o = 32; o; o >>= 1) c_t += __shfl_xor(c_t, o, 64);
        __syncthreads();
        if (lane == 0) sredi[wave] = c_t;
        __syncthreads();
        int cnt = sredi[0] + sredi[1] + sredi[2] + sredi[3];
        if (cnt < K) hi = mid; else lo = mid + 1;
    }
    float v = __uint_as_float(lo);       // K-th largest negative CE
    int c_t = 0; float s_t = 0.0f;
    for (int p = t; p < NP; p += 256) {
        float x = ce_s[p];
        if (x > v) { c_t++; s_t += x; }
    }
    #pragma unroll
    for (int o = 32; o; o >>= 1) {
        c_t += __shfl_xor(c_t, o, 64);
        s_t += __shfl_xor(s_t, o, 64);
    }
    __syncthreads();
    if (lane == 0) { sredi[wave] = c_t; sredf[wave] = s_t; }
    __syncthreads();
    if (t == 0) {
        int   cnt = sredi[0] + sredi[1] + sredi[2] + sredi[3];
        float sgt = sredf[0] + sredf[1] + sredf[2] + sredf[3];
        loss_c_b[b] = spos_b[b] + sgt + (float)(K - cnt) * v;
    }
}

__global__ void k_final(const float* __restrict__ acc,
                        const float* __restrict__ loss_c_b,
                        const int* __restrict__ npos_b,
                        float* __restrict__ out)
{
    const int t = threadIdx.x;           // 64 threads
    float lc = loss_c_b[t];
    int   np = npos_b[t];
    #pragma unroll
    for (int o = 32; o; o >>= 1) {
        lc += __shfl_xor(lc, o, 64);
        np += __shfl_xor(np, o, 64);
    }
    if (t == 0) {
        float N = (float)np;
        out[0] = acc[0] / N;
        out[1] = lc / N;
        out[2] = acc[1] / N;
    }
}

extern "C" void kernel_launch(void* const* d_in, const int* in_sizes, int n_in,
                              void* d_out, int out_size, void* d_ws, size_t ws_size,
                              hipStream_t stream)
{
    const float* loc_data  = (const float*)d_in[0];
    const float* conf_data = (const float*)d_in[1];
    const float* fc_data   = (const float*)d_in[2];
    const float* loc_t     = (const float*)d_in[3];
    const float* fc_t      = (const float*)d_in[4];
    const int*   conf_t    = (const int*)d_in[5];
    float* out = (float*)d_out;

    float* ce       = (float*)d_ws;
    float* acc      = ce + BP;           // [2]
    int*   npos_b   = (int*)(acc + 2);   // [64]
    float* spos_b   = (float*)(npos_b + 64);
    float* sneg_b   = spos_b + 64;
    float* loss_c_b = sneg_b + 64;

    hipLaunchKernelGGL(k_init,  dim3(1), dim3(256), 0, stream, acc);
    hipLaunchKernelGGL(k_main,  dim3(PBLK, NB), dim3(256), 0, stream,
                       loc_data, conf_data, fc_data, loc_t, fc_t, conf_t,
                       ce, acc, npos_b, spos_b, sneg_b);
    hipLaunchKernelGGL(k_batch, dim3(NB), dim3(256), 0, stream,
                       ce, conf_t, npos_b, spos_b, sneg_b, loss_c_b);
    hipLaunchKernelGGL(k_final, dim3(1), dim3(64), 0, stream,
                       acc, loss_c_b, npos_b, out);
}

// Round 2
// 321.845 us; speedup vs baseline: 1.0532x; 1.0532x over previous
//
#include <hip/hip_runtime.h>

// MultiBoxLoss_four_corners — B=64, P=8732, C=81, NEG_POS_RATIO=3
// Outputs: (loss_l/N, loss_c/N, loss_four_corners/N) -> d_out[0..2] (f32)
//
// R4: R3's LDS staging serialized (runtime-trip copy loop -> load/waitcnt(0)/
// ds_write per iter + __syncthreads vmcnt drain). Now: global_load_lds DMA
// (width 16, no VGPR roundtrip, no ds_write conflicts), double-buffered
// 32-row phases, raw s_barrier + counted s_waitcnt vmcnt(3) so next-phase
// loads stay in flight across the barrier (T3+T4 pattern).

#define NB 64
#define NP 8732
#define NC 81
constexpr int BP = NB * NP;              // 558848
constexpr int PBLK = (NP + 255) / 256;   // 35 blocks per batch (tail 28)
constexpr int PROWS = 32;                // rows per stage phase
constexpr int TFLOAT = 11 * 256;         // 2816 floats per buffer (11 x 1KB chunks)

__device__ inline float sl1(float d) {
    d = fabsf(d);
    return d < 1.0f ? 0.5f * d * d : d - 0.5f;
}

__device__ __forceinline__ void gload_lds16(const float* g, float* l) {
    __builtin_amdgcn_global_load_lds(
        (const __attribute__((address_space(1))) void*)g,
        (__attribute__((address_space(3))) void*)l,
        16, 0, 0);
}

// ws layout: ce[BP] | acc[2] | npos_b[64](int) | spos_b[64] | sneg_b[64] | loss_c_b[64]
__global__ void k_init(float* acc_area) {
    if (threadIdx.x < 194) acc_area[threadIdx.x] = 0.0f;
}

__global__ __launch_bounds__(256) void k_main(
    const float* __restrict__ loc_data, const float* __restrict__ conf_data,
    const float* __restrict__ fc_data,  const float* __restrict__ loc_t,
    const float* __restrict__ fc_t,     const int* __restrict__ conf_t,
    float* __restrict__ ce, float* __restrict__ acc,
    int* __restrict__ npos_b, float* __restrict__ spos_b, float* __restrict__ sneg_b)
{
    const int b  = blockIdx.y;
    const int t  = threadIdx.x;
    const int p0 = blockIdx.x << 8;
    const int nrows = min(256, NP - p0);          // 256, tail block 28
    const int nph   = (nrows + PROWS - 1) / PROWS;

    __shared__ __align__(16) float tile[2][TFLOAT];   // 22.0 KB double buffer
    __shared__ int   tgt_s[256];
    __shared__ float red[4][5];

    float l_sum = 0.0f, f_sum = 0.0f, sp = 0.0f, sn = 0.0f;
    int np = 0;

    // ---- per-prior smooth-L1 (coalesced float4) + stash targets ----
    {
        const int p = p0 + t;
        int tgt = 0;
        if (p < NP) {
            const size_t g = (size_t)b * NP + p;
            tgt = conf_t[g];
            const float posf = (tgt > 0) ? 1.0f : 0.0f;
            np = (tgt > 0) ? 1 : 0;
            float4 a4  = ((const float4*)loc_data)[g];
            float4 a4t = ((const float4*)loc_t)[g];
            l_sum = (sl1(a4.x - a4t.x) + sl1(a4.y - a4t.y) +
                     sl1(a4.z - a4t.z) + sl1(a4.w - a4t.w)) * posf;
            float4 c0 = ((const float4*)fc_data)[2 * g];
            float4 c1 = ((const float4*)fc_data)[2 * g + 1];
            float4 d0 = ((const float4*)fc_t)[2 * g];
            float4 d1 = ((const float4*)fc_t)[2 * g + 1];
            f_sum = (sl1(c0.x - d0.x) + sl1(c0.y - d0.y) + sl1(c0.z - d0.z) + sl1(c0.w - d0.w) +
                     sl1(c1.x - d1.x) + sl1(c1.y - d1.y) + sl1(c1.z - d1.z) + sl1(c1.w - d1.w)) * posf;
        }
        tgt_s[t] = tgt;
    }

    // ---- CE: DMA-staged double-buffered phases ----
    // Rows are 324B (4B-aligned). Stage from 16B-aligned base; per-phase
    // advance 32*81=2592 floats (mult of 4) -> alignment phase al is
    // block-constant.
    const size_t gbase = ((size_t)b * NP + p0) * (size_t)NC;
    const int al = (int)(gbase & 3);
    const float* conf_al = conf_data + (gbase - (size_t)al);  // 16B-aligned
    const int wave = t >> 6, lane = t & 63;
    const int r = t >> 3, sub = t & 7;

    // stage phase s: nch 1KB chunks; each wave issues EXACTLY 3 DMA instrs
    // (clamped chunks duplicate-write identical data -> benign, keeps the
    // per-wave vmcnt count uniform).
    auto stage = [&](int s) {
        const int rs  = min(PROWS, nrows - s * PROWS);
        const int nch = (al + rs * NC + 255) >> 8;            // <= 11
        const float* gb = conf_al + (size_t)s * (PROWS * NC);
        float* lb = tile[s & 1];
        #pragma unroll
        for (int i = 0; i < 3; ++i) {
            int c = wave + 4 * i;
            c = c < nch ? c : nch - 1;
            gload_lds16(gb + ((size_t)c << 8) + (lane << 2), lb + (c << 8));
        }
    };

    stage(0);
    for (int s = 0; s < nph; ++s) {
        if (s + 1 < nph) {                       // block-uniform
            stage(s + 1);
            // wait for current tile (3 newest = prefetch stay in flight)
            asm volatile("s_waitcnt vmcnt(3)\n\ts_barrier" ::: "memory");
        } else {
            asm volatile("s_waitcnt vmcnt(0)\n\ts_barrier" ::: "memory");
        }

        const int rs = min(PROWS, nrows - s * PROWS);
        if (r < rs) {
            const float* lrow = tile[s & 1] + al + r * NC;    // this row
            float s0 = 0.0f, s1 = 0.0f;
            int c = sub;                                       // sub + 8k
            #pragma unroll
            for (int k = 0; k < 5; ++k) {
                s0 += __expf(lrow[c]); c += 8;
                s1 += __expf(lrow[c]); c += 8;
            }
            if (sub == 0) s0 += __expf(lrow[80]);
            float ss = s0 + s1;
            ss += __shfl_xor(ss, 1, 64);                       // 8-lane combine
            ss += __shfl_xor(ss, 2, 64);
            ss += __shfl_xor(ss, 4, 64);
            if (sub == 0) {
                const int pl = s * PROWS + r;
                const int tgt = tgt_s[pl];
                const float cev = __logf(ss) - lrow[tgt];
                ce[(size_t)b * NP + (size_t)(p0 + pl)] = cev;
                if (tgt > 0) sp += cev; else sn += cev;
            }
        }
        // reads of tile[s&1] done before next iter's stage(s+2) overwrites it
        asm volatile("s_barrier" ::: "memory");
    }

    // ---- block reduce 5 values -> atomics ----
    float vnp = (float)np;
    #pragma unroll
    for (int o = 32; o; o >>= 1) {
        l_sum += __shfl_xor(l_sum, o, 64);
        f_sum += __shfl_xor(f_sum, o, 64);
        sp    += __shfl_xor(sp, o, 64);
        sn    += __shfl_xor(sn, o, 64);
        vnp   += __shfl_xor(vnp, o, 64);
    }
    if (lane == 0) {
        red[wave][0] = l_sum; red[wave][1] = f_sum;
        red[wave][2] = sp;    red[wave][3] = sn;   red[wave][4] = vnp;
    }
    __syncthreads();
    if (t == 0) {
        float rl = 0, rf = 0, rp = 0, rn = 0, rc = 0;
        #pragma unroll
        for (int w = 0; w < 4; ++w) {
            rl += red[w][0]; rf += red[w][1]; rp += red[w][2];
            rn += red[w][3]; rc += red[w][4];
        }
        atomicAdd(&acc[0], rl);
        atomicAdd(&acc[1], rf);
        atomicAdd(&spos_b[b], rp);
        atomicAdd(&sneg_b[b], rn);
        atomicAdd(&npos_b[b], (int)rc);
    }
}

// One block per batch. Common path: O(1). Rare path: top-K via bit binary search.
__global__ __launch_bounds__(256) void k_batch(
    const float* __restrict__ ce, const int* __restrict__ conf_t,
    const int* __restrict__ npos_b, const float* __restrict__ spos_b,
    const float* __restrict__ sneg_b, float* __restrict__ loss_c_b)
{
    const int b = blockIdx.x;
    const int t = threadIdx.x;
    const int npos    = npos_b[b];
    const int nneg    = NP - npos;
    const int num_neg = min(3 * npos, NP - 1);

    if (num_neg >= nneg) {              // all negatives selected (this dataset)
        if (t == 0) loss_c_b[b] = spos_b[b] + sneg_b[b];
        return;
    }
    if (num_neg <= 0) {
        if (t == 0) loss_c_b[b] = spos_b[b];
        return;
    }

    // general path: stage negative CE into LDS (positives -> -1), top-K sum
    __shared__ float ce_s[NP];
    __shared__ float sredf[4];
    __shared__ int   sredi[4];
    const float* crow = ce + (size_t)b * NP;
    const int*   trow = conf_t + (size_t)b * NP;
    for (int p = t; p < NP; p += 256)
        ce_s[p] = (trow[p] > 0) ? -1.0f : crow[p];
    __syncthreads();

    const int wave = t >> 6, lane = t & 63;
    const int K = num_neg;
    unsigned lo = 0u, hi = 0x7f800000u;
    while (lo < hi) {
        unsigned mid = lo + ((hi - lo) >> 1);
        float v = __uint_as_float(mid);
        int c_t = 0;
        for (int p = t; p < NP; p += 256) c_t += (ce_s[p] > v) ? 1 : 0;
        #pragma unroll
        for (int o = 32; o; o >>= 1) c_t += __shfl_xor(c_t, o, 64);
        __syncthreads();
        if (lane == 0) sredi[wave] = c_t;
        __syncthreads();
        int cnt = sredi[0] + sredi[1] + sredi[2] + sredi[3];
        if (cnt < K) hi = mid; else lo = mid + 1;
    }
    float v = __uint_as_float(lo);       // K-th largest negative CE
    int c_t = 0; float s_t = 0.0f;
    for (int p = t; p < NP; p += 256) {
        float x = ce_s[p];
        if (x > v) { c_t++; s_t += x; }
    }
    #pragma unroll
    for (int o = 32; o; o >>= 1) {
        c_t += __shfl_xor(c_t, o, 64);
        s_t += __shfl_xor(s_t, o, 64);
    }
    __syncthreads();
    if (lane == 0) { sredi[wave] = c_t; sredf[wave] = s_t; }
    __syncthreads();
    if (t == 0) {
        int   cnt = sredi[0] + sredi[1] + sredi[2] + sredi[3];
        float sgt = sredf[0] + sredf[1] + sredf[2] + sredf[3];
        loss_c_b[b] = spos_b[b] + sgt + (float)(K - cnt) * v;
    }
}

__global__ void k_final(const float* __restrict__ acc,
                        const float* __restrict__ loss_c_b,
                        const int* __restrict__ npos_b,
                        float* __restrict__ out)
{
    const int t = threadIdx.x;           // 64 threads
    float lc = loss_c_b[t];
    int   np = npos_b[t];
    #pragma unroll
    for (int o = 32; o; o >>= 1) {
        lc += __shfl_xor(lc, o, 64);
        np += __shfl_xor(np, o, 64);
    }
    if (t == 0) {
        float N = (float)np;
        out[0] = acc[0] / N;
        out[1] = lc / N;
        out[2] = acc[1] / N;
    }
}

extern "C" void kernel_launch(void* const* d_in, const int* in_sizes, int n_in,
                              void* d_out, int out_size, void* d_ws, size_t ws_size,
                              hipStream_t stream)
{
    const float* loc_data  = (const float*)d_in[0];
    const float* conf_data = (const float*)d_in[1];
    const float* fc_data   = (const float*)d_in[2];
    const float* loc_t     = (const float*)d_in[3];
    const float* fc_t      = (const float*)d_in[4];
    const int*   conf_t    = (const int*)d_in[5];
    float* out = (float*)d_out;

    float* ce       = (float*)d_ws;
    float* acc      = ce + BP;           // [2]
    int*   npos_b   = (int*)(acc + 2);   // [64]
    float* spos_b   = (float*)(npos_b + 64);
    float* sneg_b   = spos_b + 64;
    float* loss_c_b = sneg_b + 64;

    hipLaunchKernelGGL(k_init,  dim3(1), dim3(256), 0, stream, acc);
    hipLaunchKernelGGL(k_main,  dim3(PBLK, NB), dim3(256), 0, stream,
                       loc_data, conf_data, fc_data, loc_t, fc_t, conf_t,
                       ce, acc, npos_b, spos_b, sneg_b);
    hipLaunchKernelGGL(k_batch, dim3(NB), dim3(256), 0, stream,
                       ce, conf_t, npos_b, spos_b, sneg_b, loss_c_b);
    hipLaunchKernelGGL(k_final, dim3(1), dim3(64), 0, stream,
                       acc, loss_c_b, npos_b, out);
}